// Round 13
// baseline (65.860 us; speedup 1.0000x reference)
//
#include <hip/hip_runtime.h>

typedef __bf16 bf16x8 __attribute__((ext_vector_type(8)));
typedef float f32x4 __attribute__((ext_vector_type(4)));
typedef unsigned short u16x8 __attribute__((ext_vector_type(8)));
typedef unsigned short u16x4 __attribute__((ext_vector_type(4)));

#define B_ 32
#define CC 512
#define HW 192
#define C8_ 64
#define NTRI 528
#define NG2 1056          // 2 half-tiles (96x192) per pair
#define HBUF_B 18432      // one buffer: A(96x32) + B(192x32) bf16, 64B rows

__device__ inline unsigned short f2bf(float f) {
    unsigned u = __float_as_uint(f);
    unsigned r = (u + 0x7FFFu + ((u >> 16) & 1u)) >> 16;
    return (unsigned short)r;
}

__device__ inline void gload16(const void* g, void* l) {
    __builtin_amdgcn_global_load_lds(
        (const __attribute__((address_space(1))) unsigned*)g,
        (__attribute__((address_space(3))) unsigned*)l,
        16, 0, 0);
}

// ---------------- Kernel 1 (fused prep): transpose + weight precast ---------
__global__ void prep(const float* __restrict__ x,
                     const float* __restrict__ Wq, const float* __restrict__ Wk,
                     unsigned short* __restrict__ xt,
                     unsigned short* __restrict__ wqb, unsigned short* __restrict__ wkb) {
    __shared__ unsigned short tile[64 * 64];
    int t = threadIdx.x;
    if (blockIdx.x >= 96) {
        int id = (blockIdx.x - 96) * 8 + blockIdx.y;     // 0..63
        const float* src = (id < 32) ? Wq : Wk;
        unsigned short* dst = (id < 32) ? wqb : wkb;
        int base = (id & 31) * 1024 + t * 4;
        f32x4 a = *(const f32x4*)(src + base);
        u16x4 o;
        #pragma unroll
        for (int e = 0; e < 4; ++e) o[e] = f2bf(a[e]);
        *(u16x4*)(dst + base) = o;
        return;
    }
    int b = blockIdx.x / 3, mt = blockIdx.x % 3;
    int m0 = mt * 64, c0 = blockIdx.y * 64;
    const float* xb = x + (size_t)b * CC * HW + (size_t)c0 * HW + m0;

    int mq = t & 15, cl0 = t >> 4;
    int sw = (mq & 7) << 3;
    #pragma unroll
    for (int rd = 0; rd < 4; ++rd) {
        int cl = rd * 16 + cl0;
        f32x4 v = *(const f32x4*)(xb + cl * HW + mq * 4);
        #pragma unroll
        for (int e = 0; e < 4; ++e)
            tile[(mq * 4 + e) * 64 + (cl ^ sw)] = f2bf(v[e]);
    }
    __syncthreads();
    unsigned short* xo = xt + ((size_t)b * HW + m0) * CC + c0;
    int kc = t & 7, mr0 = t >> 3;
    #pragma unroll
    for (int rd = 0; rd < 2; ++rd) {
        int mr = rd * 32 + mr0;
        u16x8 v = *(const u16x8*)&tile[mr * 64 + ((kc << 3) ^ (((mr >> 2) & 7) << 3))];
        *(u16x8*)(xo + (size_t)mr * CC + kc * 8) = v;
    }
}

// ---------------- Kernel 2: q/k projections via MFMA (round-7 verbatim) -----
__global__ __launch_bounds__(256) void pam_qk(
        const unsigned short* __restrict__ xt,
        const unsigned short* __restrict__ wqb, const unsigned short* __restrict__ wkb,
        const float* __restrict__ bq, const float* __restrict__ bk,
        unsigned short* __restrict__ qo, unsigned short* __restrict__ ko) {
    int b = blockIdx.x, m0 = blockIdx.y * 48;
    int tid = threadIdx.x, w = tid >> 6, lane = tid & 63;
    int l15 = lane & 15, lq = lane >> 4;
    int qc = w * 16 + l15;

    f32x4 accq[3], acck[3];
    #pragma unroll
    for (int i = 0; i < 3; ++i) {
        accq[i] = (f32x4){0.f, 0.f, 0.f, 0.f};
        acck[i] = (f32x4){0.f, 0.f, 0.f, 0.f};
    }

    const unsigned short* xb = xt + ((size_t)b * HW + m0) * CC;
    const unsigned short* wqp = wqb + (size_t)qc * CC;
    const unsigned short* wkp = wkb + (size_t)qc * CC;

    for (int kt = 0; kt < 16; ++kt) {
        int ko8 = kt * 32 + lq * 8;
        bf16x8 wqf = *(const bf16x8*)(wqp + ko8);
        bf16x8 wkf = *(const bf16x8*)(wkp + ko8);
        bf16x8 af[3];
        #pragma unroll
        for (int i = 0; i < 3; ++i)
            af[i] = *(const bf16x8*)(xb + (i * 16 + l15) * CC + ko8);
        #pragma unroll
        for (int i = 0; i < 3; ++i) {
            accq[i] = __builtin_amdgcn_mfma_f32_16x16x32_bf16(af[i], wqf, accq[i], 0, 0, 0);
            acck[i] = __builtin_amdgcn_mfma_f32_16x16x32_bf16(af[i], wkf, acck[i], 0, 0, 0);
        }
    }

    float bqv = bq[qc], bkv = bk[qc];
    #pragma unroll
    for (int i = 0; i < 3; ++i) {
        #pragma unroll
        for (int r = 0; r < 4; ++r) {
            int m = m0 + i * 16 + lq * 4 + r;
            qo[((size_t)b * HW + m) * C8_ + qc] = f2bf(accq[i][r] + bqv);
            ko[((size_t)b * HW + m) * C8_ + qc] = f2bf(acck[i][r] + bkv);
        }
    }
}

// ---------------- Kernel 3: Gram half-tiles, counted-vmcnt 3-buffer ---------
// 1056 blocks x 384 thr (6 waves, 2x3 of 48x64). BK=32, 16 K-steps, stage
// 2 ahead, s_waitcnt vmcnt(3) + raw s_barrier (no vmcnt(0) drain in loop).
// Rowmax (full 192) -> out[p][g][96h+m]; colmax partial -> ws2[pair][h][n].
__global__ __launch_bounds__(384, 3) void gram4(const unsigned short* __restrict__ xt,
                                                float* __restrict__ out,
                                                float* __restrict__ ws2) {
    __shared__ __attribute__((aligned(16))) char smem[3 * HBUF_B];

    int tid = threadIdx.x;
    int bid = (blockIdx.x & 7) * 132 + (blockIdx.x >> 3);   // 1056 = 8*132
    int pairid = bid >> 1, h = bid & 1;
    int idx = pairid, g = 0;
    while (idx >= B_ - g) { idx -= B_ - g; ++g; }
    int p = g + idx;

    const unsigned short* xga = xt + ((size_t)g * HW + 96 * h) * CC;  // A: 96 rows
    const unsigned short* xp  = xt + (size_t)p * HW * CC;             // B: 192 rows

    int w = tid / 64, lane = tid & 63;
    int wr = w / 3, cg = w % 3;             // 2 x 3 wave grid; tile 48 x 64
    int l15 = lane & 15, lq = lane >> 4;

    // staging: 1152 chunks of 16B per buffer, 3 per thread, LDS linear.
    // q<384: A (row q>>2, slot q&3); else B. Source pre-applies inverse swz.
    const unsigned short* sp[3];
    unsigned lo[3];
    #pragma unroll
    for (int ci = 0; ci < 3; ++ci) {
        int q = tid + 384 * ci;
        lo[ci] = (unsigned)q * 16;
        int q2 = (q < 384) ? q : q - 384;
        int r = q2 >> 2, s = q2 & 3;
        sp[ci] = ((q < 384) ? xga : xp) + r * CC + ((s ^ ((r >> 1) & 3)) << 3);
    }

    // read offsets (byte): row*64 + ((lq ^ ((row>>1)&3))<<4); B region at 6144
    unsigned aoff[3], boff[4];
    #pragma unroll
    for (int i = 0; i < 3; ++i) {
        int row = wr * 48 + i * 16 + l15;
        aoff[i] = (unsigned)row * 64 + ((unsigned)(lq ^ ((row >> 1) & 3)) << 4);
    }
    #pragma unroll
    for (int j = 0; j < 4; ++j) {
        int n = cg * 64 + j * 16 + l15;
        boff[j] = 6144u + (unsigned)n * 64 + ((unsigned)(lq ^ ((n >> 1) & 3)) << 4);
    }

    f32x4 acc[3][4];
    #pragma unroll
    for (int i = 0; i < 3; ++i)
        #pragma unroll
        for (int j = 0; j < 4; ++j)
            acc[i][j] = (f32x4){0.f, 0.f, 0.f, 0.f};

    #define STG4(buf, kt)                                                      \
        {                                                                      \
            char* base = smem + (buf) * HBUF_B;                                \
            int k0 = (kt) * 32;                                                \
            gload16(sp[0] + k0, base + lo[0]);                                 \
            gload16(sp[1] + k0, base + lo[1]);                                 \
            gload16(sp[2] + k0, base + lo[2]);                                 \
        }

    #define CMP4(buf)                                                          \
        {                                                                      \
            const char* Bb = smem + (buf) * HBUF_B;                            \
            bf16x8 af[3], bfr[4];                                              \
            _Pragma("unroll")                                                  \
            for (int i = 0; i < 3; ++i)                                        \
                af[i] = *(const bf16x8*)(Bb + aoff[i]);                        \
            _Pragma("unroll")                                                  \
            for (int j = 0; j < 4; ++j)                                        \
                bfr[j] = *(const bf16x8*)(Bb + boff[j]);                       \
            _Pragma("unroll")                                                  \
            for (int i = 0; i < 3; ++i)                                        \
                _Pragma("unroll")                                              \
                for (int j = 0; j < 4; ++j)                                    \
                    acc[i][j] = __builtin_amdgcn_mfma_f32_16x16x32_bf16(       \
                        af[i], bfr[j], acc[i][j], 0, 0, 0);                    \
        }

    #define WT3() asm volatile("s_waitcnt vmcnt(3)" ::: "memory")
    #define WT0() asm volatile("s_waitcnt vmcnt(0)" ::: "memory")
    #define BR()  { __builtin_amdgcn_sched_barrier(0); __builtin_amdgcn_s_barrier(); }

    STG4(0, 0);
    STG4(1, 1);                             // 6 loads in flight per wave

    #pragma unroll
    for (int kt = 0; kt < 16; ++kt) {
        if (kt < 15) { WT3(); } else { WT0(); }
        BR();
        if (kt < 14) STG4((kt + 2) % 3, kt + 2);
        CMP4(kt % 3);
    }
    __syncthreads();

    // ---- epilogue (aliases buffer 0 after barrier)
    float* rowred = (float*)smem;            // [3][96]
    float* colred = (float*)(smem + 1152);   // [2][192]

    #pragma unroll
    for (int i = 0; i < 3; ++i) {            // rowmax over this wave's 64 n
        float rm[4];
        #pragma unroll
        for (int r = 0; r < 4; ++r) rm[r] = -1e30f;
        #pragma unroll
        for (int j = 0; j < 4; ++j)
            #pragma unroll
            for (int r = 0; r < 4; ++r)
                rm[r] = fmaxf(rm[r], acc[i][j][r]);
        #pragma unroll
        for (int msk = 1; msk <= 8; msk <<= 1)
            #pragma unroll
            for (int r = 0; r < 4; ++r)
                rm[r] = fmaxf(rm[r], __shfl_xor(rm[r], msk));
        if (l15 == 0) {
            #pragma unroll
            for (int r = 0; r < 4; ++r)
                rowred[cg * 96 + wr * 48 + i * 16 + lq * 4 + r] = rm[r];
        }
    }
    #pragma unroll
    for (int j = 0; j < 4; ++j) {            // colmax over this wave's 48 m
        float cm = -1e30f;
        #pragma unroll
        for (int i = 0; i < 3; ++i)
            #pragma unroll
            for (int r = 0; r < 4; ++r)
                cm = fmaxf(cm, acc[i][j][r]);
        cm = fmaxf(cm, __shfl_xor(cm, 16));
        cm = fmaxf(cm, __shfl_xor(cm, 32));
        if (lane < 16) colred[wr * 192 + cg * 64 + j * 16 + l15] = cm;
    }
    __syncthreads();
    if (tid < 96) {
        float v = fmaxf(fmaxf(rowred[tid], rowred[96 + tid]), rowred[192 + tid]);
        out[((size_t)p * B_ + g) * HW + 96 * h + tid] = v;
    } else if (tid < 288) {
        int n = tid - 96;
        ws2[(size_t)pairid * 384 + h * 192 + n] = fmaxf(colred[n], colred[192 + n]);
    }
}

// ---------------- Kernel 4 (fused): pam_energy (0..127) + finalize (128..655)
__global__ __launch_bounds__(256) void energy_fin(
        const unsigned short* __restrict__ qo,
        const unsigned short* __restrict__ ko,
        const float* __restrict__ ws2,
        float* __restrict__ out) {
    int tid = threadIdx.x;
    if (blockIdx.x >= 128) {
        int pairid = blockIdx.x - 128;
        int idx = pairid, g = 0;
        while (idx >= B_ - g) { idx -= B_ - g; ++g; }
        int p = g + idx;
        if (tid < HW)
            out[((size_t)g * B_ + p) * HW + tid] =
                fmaxf(ws2[(size_t)pairid * 384 + tid], ws2[(size_t)pairid * 384 + 192 + tid]);
        return;
    }
    int b = blockIdx.x >> 2, m0 = (blockIdx.x & 3) * 48;
    int w = tid >> 6, lane = tid & 63;
    int l15 = lane & 15, lq = lane >> 4;
    int n0 = w * 48;

    f32x4 acc[3][3];
    #pragma unroll
    for (int i = 0; i < 3; ++i)
        #pragma unroll
        for (int j = 0; j < 3; ++j)
            acc[i][j] = (f32x4){0.f, 0.f, 0.f, 0.f};

    const unsigned short* qb = qo + ((size_t)b * HW + m0) * C8_;
    const unsigned short* kb = ko + ((size_t)b * HW + n0) * C8_;

    #pragma unroll
    for (int kt = 0; kt < 2; ++kt) {
        int ko8 = kt * 32 + lq * 8;
        bf16x8 af[3], bfr[3];
        #pragma unroll
        for (int i = 0; i < 3; ++i)
            af[i] = *(const bf16x8*)(qb + (i * 16 + l15) * C8_ + ko8);
        #pragma unroll
        for (int j = 0; j < 3; ++j)
            bfr[j] = *(const bf16x8*)(kb + (j * 16 + l15) * C8_ + ko8);
        #pragma unroll
        for (int i = 0; i < 3; ++i)
            #pragma unroll
            for (int j = 0; j < 3; ++j)
                acc[i][j] = __builtin_amdgcn_mfma_f32_16x16x32_bf16(af[i], bfr[j], acc[i][j], 0, 0, 0);
    }

    __shared__ float red[4][48];
    #pragma unroll
    for (int i = 0; i < 3; ++i) {
        float rm[4];
        #pragma unroll
        for (int r = 0; r < 4; ++r) rm[r] = -1e30f;
        #pragma unroll
        for (int j = 0; j < 3; ++j)
            #pragma unroll
            for (int r = 0; r < 4; ++r)
                rm[r] = fmaxf(rm[r], acc[i][j][r]);
        #pragma unroll
        for (int msk = 1; msk <= 8; msk <<= 1)
            #pragma unroll
            for (int r = 0; r < 4; ++r)
                rm[r] = fmaxf(rm[r], __shfl_xor(rm[r], msk));
        if (l15 == 0) {
            #pragma unroll
            for (int r = 0; r < 4; ++r)
                red[w][i * 16 + lq * 4 + r] = rm[r];
        }
    }
    __syncthreads();
    if (tid < 48) {
        float v = fmaxf(fmaxf(red[0][tid], red[1][tid]),
                        fmaxf(red[2][tid], red[3][tid]));
        out[((size_t)B_ * B_ + b) * HW + m0 + tid] = v;
    }
}

extern "C" void kernel_launch(void* const* d_in, const int* in_sizes, int n_in,
                              void* d_out, int out_size, void* d_ws, size_t ws_size,
                              hipStream_t stream) {
    (void)in_sizes; (void)n_in; (void)out_size; (void)ws_size;
    const float* x  = (const float*)d_in[0];
    const float* Wq = (const float*)d_in[1];
    const float* bq = (const float*)d_in[2];
    const float* Wk = (const float*)d_in[3];
    const float* bk = (const float*)d_in[4];
    float* out = (float*)d_out;

    char* ws = (char*)d_ws;
    unsigned short* xt  = (unsigned short*)ws;                        // 6291456 B
    unsigned short* wqb = (unsigned short*)(ws + 6291456);            // 65536 B
    unsigned short* wkb = (unsigned short*)(ws + 6291456 + 65536);    // 65536 B
    unsigned short* qbuf = (unsigned short*)(ws + 6291456 + 131072);  // 786432 B
    unsigned short* kbuf = (unsigned short*)(ws + 6291456 + 131072 + 786432);
    float* ws2 = (float*)(ws + 6291456 + 131072 + 2 * 786432);        // 811008 B

    prep<<<dim3(104, 8), dim3(256), 0, stream>>>(x, Wq, Wk, xt, wqb, wkb);
    pam_qk<<<dim3(32, 4), dim3(256), 0, stream>>>(xt, wqb, wkb, bq, bk, qbuf, kbuf);
    gram4<<<dim3(NG2), dim3(384), 0, stream>>>(xt, out, ws2);
    energy_fin<<<dim3(656), dim3(256), 0, stream>>>(qbuf, kbuf, ws2, out);
}

// Round 14
// 58.422 us; speedup vs baseline: 1.1273x; 1.1273x over previous
//
#include <hip/hip_runtime.h>

typedef __bf16 bf16x8 __attribute__((ext_vector_type(8)));
typedef float f32x4 __attribute__((ext_vector_type(4)));
typedef unsigned short u16x8 __attribute__((ext_vector_type(8)));
typedef unsigned short u16x4 __attribute__((ext_vector_type(4)));

#define B_ 32
#define CC 512
#define HW 192
#define C8_ 64
#define NTRI 528
#define FBUF_B 24576      // one buffer: A(192x32) + B(192x32) bf16, 64B rows

__device__ inline unsigned short f2bf(float f) {
    unsigned u = __float_as_uint(f);
    unsigned r = (u + 0x7FFFu + ((u >> 16) & 1u)) >> 16;
    return (unsigned short)r;
}

__device__ inline void gload16(const void* g, void* l) {
    __builtin_amdgcn_global_load_lds(
        (const __attribute__((address_space(1))) unsigned*)g,
        (__attribute__((address_space(3))) unsigned*)l,
        16, 0, 0);
}

// ---------------- Kernel 1 (fused prep): transpose + weight precast ---------
__global__ void prep(const float* __restrict__ x,
                     const float* __restrict__ Wq, const float* __restrict__ Wk,
                     unsigned short* __restrict__ xt,
                     unsigned short* __restrict__ wqb, unsigned short* __restrict__ wkb) {
    __shared__ unsigned short tile[64 * 64];
    int t = threadIdx.x;
    if (blockIdx.x >= 96) {
        int id = (blockIdx.x - 96) * 8 + blockIdx.y;     // 0..63
        const float* src = (id < 32) ? Wq : Wk;
        unsigned short* dst = (id < 32) ? wqb : wkb;
        int base = (id & 31) * 1024 + t * 4;
        f32x4 a = *(const f32x4*)(src + base);
        u16x4 o;
        #pragma unroll
        for (int e = 0; e < 4; ++e) o[e] = f2bf(a[e]);
        *(u16x4*)(dst + base) = o;
        return;
    }
    int b = blockIdx.x / 3, mt = blockIdx.x % 3;
    int m0 = mt * 64, c0 = blockIdx.y * 64;
    const float* xb = x + (size_t)b * CC * HW + (size_t)c0 * HW + m0;

    int mq = t & 15, cl0 = t >> 4;
    int sw = (mq & 7) << 3;
    #pragma unroll
    for (int rd = 0; rd < 4; ++rd) {
        int cl = rd * 16 + cl0;
        f32x4 v = *(const f32x4*)(xb + cl * HW + mq * 4);
        #pragma unroll
        for (int e = 0; e < 4; ++e)
            tile[(mq * 4 + e) * 64 + (cl ^ sw)] = f2bf(v[e]);
    }
    __syncthreads();
    unsigned short* xo = xt + ((size_t)b * HW + m0) * CC + c0;
    int kc = t & 7, mr0 = t >> 3;
    #pragma unroll
    for (int rd = 0; rd < 2; ++rd) {
        int mr = rd * 32 + mr0;
        u16x8 v = *(const u16x8*)&tile[mr * 64 + ((kc << 3) ^ (((mr >> 2) & 7) << 3))];
        *(u16x8*)(xo + (size_t)mr * CC + kc * 8) = v;
    }
}

// ---------------- Kernel 2: q/k projections via MFMA (round-7 verbatim) -----
__global__ __launch_bounds__(256) void pam_qk(
        const unsigned short* __restrict__ xt,
        const unsigned short* __restrict__ wqb, const unsigned short* __restrict__ wkb,
        const float* __restrict__ bq, const float* __restrict__ bk,
        unsigned short* __restrict__ qo, unsigned short* __restrict__ ko) {
    int b = blockIdx.x, m0 = blockIdx.y * 48;
    int tid = threadIdx.x, w = tid >> 6, lane = tid & 63;
    int l15 = lane & 15, lq = lane >> 4;
    int qc = w * 16 + l15;

    f32x4 accq[3], acck[3];
    #pragma unroll
    for (int i = 0; i < 3; ++i) {
        accq[i] = (f32x4){0.f, 0.f, 0.f, 0.f};
        acck[i] = (f32x4){0.f, 0.f, 0.f, 0.f};
    }

    const unsigned short* xb = xt + ((size_t)b * HW + m0) * CC;
    const unsigned short* wqp = wqb + (size_t)qc * CC;
    const unsigned short* wkp = wkb + (size_t)qc * CC;

    for (int kt = 0; kt < 16; ++kt) {
        int ko8 = kt * 32 + lq * 8;
        bf16x8 wqf = *(const bf16x8*)(wqp + ko8);
        bf16x8 wkf = *(const bf16x8*)(wkp + ko8);
        bf16x8 af[3];
        #pragma unroll
        for (int i = 0; i < 3; ++i)
            af[i] = *(const bf16x8*)(xb + (i * 16 + l15) * CC + ko8);
        #pragma unroll
        for (int i = 0; i < 3; ++i) {
            accq[i] = __builtin_amdgcn_mfma_f32_16x16x32_bf16(af[i], wqf, accq[i], 0, 0, 0);
            acck[i] = __builtin_amdgcn_mfma_f32_16x16x32_bf16(af[i], wkf, acck[i], 0, 0, 0);
        }
    }

    float bqv = bq[qc], bkv = bk[qc];
    #pragma unroll
    for (int i = 0; i < 3; ++i) {
        #pragma unroll
        for (int r = 0; r < 4; ++r) {
            int m = m0 + i * 16 + lq * 4 + r;
            qo[((size_t)b * HW + m) * C8_ + qc] = f2bf(accq[i][r] + bqv);
            ko[((size_t)b * HW + m) * C8_ + qc] = f2bf(acck[i][r] + bkv);
        }
    }
}

// ---------------- Kernel 3: Gram full tiles, 4 waves of 96x96, 2 blk/CU -----
// 528 blocks x 256 thr (4 waves, 2x2 of 96x96). BK=32, dbuf, drain barriers.
// Ratio: 12 ds_read_b128 -> 36 MFMAs per wave-step. LDS 49KB static.
// Both rowmax and colmax complete in-block.
__global__ __launch_bounds__(256, 2) void gram5(const unsigned short* __restrict__ xt,
                                                float* __restrict__ out) {
    __shared__ __attribute__((aligned(16))) char smem[2 * FBUF_B];

    int tid = threadIdx.x;
    int bid = (blockIdx.x & 7) * 66 + (blockIdx.x >> 3);   // 528 = 8*66
    int idx = bid, g = 0;
    while (idx >= B_ - g) { idx -= B_ - g; ++g; }
    int p = g + idx;

    const unsigned short* xg = xt + (size_t)g * HW * CC;
    const unsigned short* xp = xt + (size_t)p * HW * CC;

    int w = tid >> 6, lane = tid & 63;
    int wr = w >> 1, wc = w & 1;                // 2 x 2 wave grid, 96x96 each
    int l15 = lane & 15, lq = lane >> 4;

    // staging: per buffer 1536 16B-chunks (A rows 0..191 then B rows 0..191),
    // 6 chunks/thread. q = tid + 256*ci: ci 0..2 -> A row (tid>>2)+64ci,
    // ci 3..5 -> B row (tid>>2)+64(ci-3). slot s = tid&3 (fixed).
    // Source pre-applies inverse swizzle: logical chunk s ^ ((r>>1)&3),
    // and ((r>>1)&3) == ((tid>>3)&3) for all ci (r-base even increments).
    int sc = ((tid & 3) ^ ((tid >> 3) & 3)) << 3;
    const unsigned short* baseA = xg + (size_t)(tid >> 2) * CC + sc;
    const unsigned short* baseB = xp + (size_t)(tid >> 2) * CC + sc;
    unsigned ldsA = (unsigned)tid * 16;

    // read offsets (byte): row*64 + ((lq ^ ((row>>1)&3))<<4); B region at 12288
    unsigned aoff[6], boff[6];
    #pragma unroll
    for (int i = 0; i < 6; ++i) {
        int row = wr * 96 + i * 16 + l15;
        aoff[i] = (unsigned)row * 64 + ((unsigned)(lq ^ ((row >> 1) & 3)) << 4);
    }
    #pragma unroll
    for (int j = 0; j < 6; ++j) {
        int n = wc * 96 + j * 16 + l15;
        boff[j] = 12288u + (unsigned)n * 64 + ((unsigned)(lq ^ ((n >> 1) & 3)) << 4);
    }

    f32x4 acc[6][6];
    #pragma unroll
    for (int i = 0; i < 6; ++i)
        #pragma unroll
        for (int j = 0; j < 6; ++j)
            acc[i][j] = (f32x4){0.f, 0.f, 0.f, 0.f};

    #define STG5(buf, kt)                                                      \
        {                                                                      \
            char* base = smem + (buf) * FBUF_B;                                \
            int k0 = (kt) * 32;                                                \
            _Pragma("unroll")                                                  \
            for (int ci = 0; ci < 3; ++ci) {                                   \
                gload16(baseA + k0 + ci * 64 * CC, base + ldsA + ci * 4096);   \
                gload16(baseB + k0 + ci * 64 * CC,                             \
                        base + 12288 + ldsA + ci * 4096);                      \
            }                                                                  \
        }

    #define CMP5(buf)                                                          \
        {                                                                      \
            const char* Bb = smem + (buf) * FBUF_B;                            \
            bf16x8 bfr[6];                                                     \
            _Pragma("unroll")                                                  \
            for (int j = 0; j < 6; ++j)                                        \
                bfr[j] = *(const bf16x8*)(Bb + boff[j]);                       \
            _Pragma("unroll")                                                  \
            for (int i = 0; i < 6; ++i) {                                      \
                bf16x8 a = *(const bf16x8*)(Bb + aoff[i]);                     \
                _Pragma("unroll")                                              \
                for (int j = 0; j < 6; ++j)                                    \
                    acc[i][j] = __builtin_amdgcn_mfma_f32_16x16x32_bf16(       \
                        a, bfr[j], acc[i][j], 0, 0, 0);                        \
            }                                                                  \
        }

    STG5(0, 0);
    __syncthreads();
    for (int kt = 0; kt < 16; ++kt) {
        int cur = kt & 1;
        if (kt < 15) STG5(cur ^ 1, kt + 1);
        CMP5(cur);
        __syncthreads();
    }

    // ---- epilogue (aliases smem; all K-loop LDS traffic done)
    float* colbuf = (float*)smem;            // [2][192] partial over wr
    float* rowbuf = (float*)(smem + 1536);   // [2][192] partial over wc

    #pragma unroll
    for (int i = 0; i < 6; ++i) {            // rowmax over this wave's 96 n
        float rm[4];
        #pragma unroll
        for (int r = 0; r < 4; ++r) rm[r] = -1e30f;
        #pragma unroll
        for (int j = 0; j < 6; ++j)
            #pragma unroll
            for (int r = 0; r < 4; ++r)
                rm[r] = fmaxf(rm[r], acc[i][j][r]);
        #pragma unroll
        for (int msk = 1; msk <= 8; msk <<= 1)
            #pragma unroll
            for (int r = 0; r < 4; ++r)
                rm[r] = fmaxf(rm[r], __shfl_xor(rm[r], msk));
        if (l15 == 0) {
            #pragma unroll
            for (int r = 0; r < 4; ++r)
                rowbuf[wc * HW + wr * 96 + i * 16 + lq * 4 + r] = rm[r];
        }
    }
    #pragma unroll
    for (int j = 0; j < 6; ++j) {            // colmax over this wave's 96 m
        float cm = -1e30f;
        #pragma unroll
        for (int i = 0; i < 6; ++i)
            #pragma unroll
            for (int r = 0; r < 4; ++r)
                cm = fmaxf(cm, acc[i][j][r]);
        cm = fmaxf(cm, __shfl_xor(cm, 16));
        cm = fmaxf(cm, __shfl_xor(cm, 32));
        if (lane < 16) colbuf[wr * HW + wc * 96 + j * 16 + l15] = cm;
    }
    __syncthreads();
    if (tid < HW) {
        float cmax = fmaxf(colbuf[tid], colbuf[HW + tid]);
        out[((size_t)g * B_ + p) * HW + tid] = cmax;
        float rmax = fmaxf(rowbuf[tid], rowbuf[HW + tid]);
        out[((size_t)p * B_ + g) * HW + tid] = rmax;   // same addr if g==p
    }
}

// ---------------- Kernel 4: energy = q k^T per batch, fused row-max ---------
__global__ __launch_bounds__(256) void pam_energy(
        const unsigned short* __restrict__ qo,
        const unsigned short* __restrict__ ko,
        float* __restrict__ out) {
    int b = blockIdx.x, m0 = blockIdx.y * 48;
    int tid = threadIdx.x, w = tid >> 6, lane = tid & 63;
    int l15 = lane & 15, lq = lane >> 4;
    int n0 = w * 48;

    f32x4 acc[3][3];
    #pragma unroll
    for (int i = 0; i < 3; ++i)
        #pragma unroll
        for (int j = 0; j < 3; ++j)
            acc[i][j] = (f32x4){0.f, 0.f, 0.f, 0.f};

    const unsigned short* qb = qo + ((size_t)b * HW + m0) * C8_;
    const unsigned short* kb = ko + ((size_t)b * HW + n0) * C8_;

    #pragma unroll
    for (int kt = 0; kt < 2; ++kt) {
        int ko8 = kt * 32 + lq * 8;
        bf16x8 af[3], bfr[3];
        #pragma unroll
        for (int i = 0; i < 3; ++i)
            af[i] = *(const bf16x8*)(qb + (i * 16 + l15) * C8_ + ko8);
        #pragma unroll
        for (int j = 0; j < 3; ++j)
            bfr[j] = *(const bf16x8*)(kb + (j * 16 + l15) * C8_ + ko8);
        #pragma unroll
        for (int i = 0; i < 3; ++i)
            #pragma unroll
            for (int j = 0; j < 3; ++j)
                acc[i][j] = __builtin_amdgcn_mfma_f32_16x16x32_bf16(af[i], bfr[j], acc[i][j], 0, 0, 0);
    }

    __shared__ float red[4][48];
    #pragma unroll
    for (int i = 0; i < 3; ++i) {
        float rm[4];
        #pragma unroll
        for (int r = 0; r < 4; ++r) rm[r] = -1e30f;
        #pragma unroll
        for (int j = 0; j < 3; ++j)
            #pragma unroll
            for (int r = 0; r < 4; ++r)
                rm[r] = fmaxf(rm[r], acc[i][j][r]);
        #pragma unroll
        for (int msk = 1; msk <= 8; msk <<= 1)
            #pragma unroll
            for (int r = 0; r < 4; ++r)
                rm[r] = fmaxf(rm[r], __shfl_xor(rm[r], msk));
        if (l15 == 0) {
            #pragma unroll
            for (int r = 0; r < 4; ++r)
                red[w][i * 16 + lq * 4 + r] = rm[r];
        }
    }
    __syncthreads();
    if (tid < 48) {
        float v = fmaxf(fmaxf(red[0][tid], red[1][tid]),
                        fmaxf(red[2][tid], red[3][tid]));
        out[((size_t)B_ * B_ + b) * HW + m0 + tid] = v;
    }
}

extern "C" void kernel_launch(void* const* d_in, const int* in_sizes, int n_in,
                              void* d_out, int out_size, void* d_ws, size_t ws_size,
                              hipStream_t stream) {
    (void)in_sizes; (void)n_in; (void)out_size; (void)ws_size;
    const float* x  = (const float*)d_in[0];
    const float* Wq = (const float*)d_in[1];
    const float* bq = (const float*)d_in[2];
    const float* Wk = (const float*)d_in[3];
    const float* bk = (const float*)d_in[4];
    float* out = (float*)d_out;

    char* ws = (char*)d_ws;
    unsigned short* xt  = (unsigned short*)ws;                        // 6291456 B
    unsigned short* wqb = (unsigned short*)(ws + 6291456);            // 65536 B
    unsigned short* wkb = (unsigned short*)(ws + 6291456 + 65536);    // 65536 B
    unsigned short* qbuf = (unsigned short*)(ws + 6291456 + 131072);  // 786432 B
    unsigned short* kbuf = (unsigned short*)(ws + 6291456 + 131072 + 786432);

    prep<<<dim3(104, 8), dim3(256), 0, stream>>>(x, Wq, Wk, xt, wqb, wkb);
    pam_qk<<<dim3(32, 4), dim3(256), 0, stream>>>(xt, wqb, wkb, bq, bk, qbuf, kbuf);
    gram5<<<dim3(NTRI), dim3(256), 0, stream>>>(xt, out);
    pam_energy<<<dim3(32, 4), dim3(256), 0, stream>>>(qbuf, kbuf, out);
}

// Round 15
// 51.801 us; speedup vs baseline: 1.2714x; 1.1278x over previous
//
#include <hip/hip_runtime.h>

typedef __bf16 bf16x8 __attribute__((ext_vector_type(8)));
typedef float f32x4 __attribute__((ext_vector_type(4)));
typedef unsigned short u16x8 __attribute__((ext_vector_type(8)));
typedef unsigned short u16x4 __attribute__((ext_vector_type(4)));

#define B_ 32
#define CC 512
#define HW 192
#define C8_ 64
#define NTRI 528
#define NG2 1056          // 2 half-tiles per pair (gram); raw blocks >=1056: qk-proj
#define BUF_B 36864       // one buffer: A(96x64) + B(192x64) bf16, 128B rows
#define SMEM_BYTES 73728  // 2 buffers

__device__ inline unsigned short f2bf(float f) {
    unsigned u = __float_as_uint(f);
    unsigned r = (u + 0x7FFFu + ((u >> 16) & 1u)) >> 16;
    return (unsigned short)r;
}

__device__ inline void gload16(const void* g, void* l) {
    __builtin_amdgcn_global_load_lds(
        (const __attribute__((address_space(1))) unsigned*)g,
        (__attribute__((address_space(3))) unsigned*)l,
        16, 0, 0);
}

// ---------------- Kernel 1 (fused prep): transpose + weight precast ---------
__global__ void prep(const float* __restrict__ x,
                     const float* __restrict__ Wq, const float* __restrict__ Wk,
                     unsigned short* __restrict__ xt,
                     unsigned short* __restrict__ wqb, unsigned short* __restrict__ wkb) {
    __shared__ unsigned short tile[64 * 64];
    int t = threadIdx.x;
    if (blockIdx.x >= 96) {
        int id = (blockIdx.x - 96) * 8 + blockIdx.y;     // 0..63
        const float* src = (id < 32) ? Wq : Wk;
        unsigned short* dst = (id < 32) ? wqb : wkb;
        int base = (id & 31) * 1024 + t * 4;
        f32x4 a = *(const f32x4*)(src + base);
        u16x4 o;
        #pragma unroll
        for (int e = 0; e < 4; ++e) o[e] = f2bf(a[e]);
        *(u16x4*)(dst + base) = o;
        return;
    }
    int b = blockIdx.x / 3, mt = blockIdx.x % 3;
    int m0 = mt * 64, c0 = blockIdx.y * 64;
    const float* xb = x + (size_t)b * CC * HW + (size_t)c0 * HW + m0;

    int mq = t & 15, cl0 = t >> 4;
    int sw = (mq & 7) << 3;
    #pragma unroll
    for (int rd = 0; rd < 4; ++rd) {
        int cl = rd * 16 + cl0;
        f32x4 v = *(const f32x4*)(xb + cl * HW + mq * 4);
        #pragma unroll
        for (int e = 0; e < 4; ++e)
            tile[(mq * 4 + e) * 64 + (cl ^ sw)] = f2bf(v[e]);
    }
    __syncthreads();
    unsigned short* xo = xt + ((size_t)b * HW + m0) * CC + c0;
    int kc = t & 7, mr0 = t >> 3;
    #pragma unroll
    for (int rd = 0; rd < 2; ++rd) {
        int mr = rd * 32 + mr0;
        u16x8 v = *(const u16x8*)&tile[mr * 64 + ((kc << 3) ^ (((mr >> 2) & 7) << 3))];
        *(u16x8*)(xo + (size_t)mr * CC + kc * 8) = v;
    }
}

// ---------------- Kernel 2 (fused): gram half-tiles + q/k projections -------
// raw blocks 0..1055: gram half-tile (96x192), R11-verbatim (best measured).
// raw blocks 1056..1183: q/k projection for (b, mgrp) — dispatched last,
// backfills gram's tail; round-robin XCD placement (no swizzle clustering).
__global__ __launch_bounds__(512, 4) void gram_qk(
        const unsigned short* __restrict__ xt,
        const unsigned short* __restrict__ wqb, const unsigned short* __restrict__ wkb,
        const float* __restrict__ bq, const float* __restrict__ bk,
        unsigned short* __restrict__ qo, unsigned short* __restrict__ ko,
        float* __restrict__ out, float* __restrict__ ws2) {
    extern __shared__ char smem[];

    int tid = threadIdx.x;
    int w = tid >> 6, lane = tid & 63;
    int l15 = lane & 15, lq = lane >> 4;

    if (blockIdx.x < NG2) {
        // ================= GRAM (R11 verbatim) =================
        int bid = (blockIdx.x & 7) * 132 + (blockIdx.x >> 3);   // 1056 = 8*132
        int pairid = bid >> 1, h = bid & 1;
        int idx = pairid, g = 0;
        while (idx >= B_ - g) { idx -= B_ - g; ++g; }
        int p = g + idx;

        const unsigned short* xga = xt + ((size_t)g * HW + 96 * h) * CC;  // A: 96 rows
        const unsigned short* xp  = xt + (size_t)p * HW * CC;             // B: 192 rows

        int wr = w >> 2, wc = w & 3;                // 2 x 4 wave grid

        const unsigned short* sp[5];
        unsigned lo[5];
        #pragma unroll
        for (int ci = 0; ci < 5; ++ci) {
            int R = (ci < 4) ? (w + 8 * ci) : (32 + w);
            int q = R * 64 + lane;
            if (ci == 4 && w >= 4) q = lane;        // dummy (unused)
            lo[ci] = (unsigned)q * 16;
            if (q < 768) {
                int r = q >> 3, s = q & 7;
                sp[ci] = xga + r * CC + ((s ^ (r & 7)) << 3);
            } else {
                int q2 = q - 768, n = q2 >> 3, s = q2 & 7;
                sp[ci] = xp + n * CC + ((s ^ (n & 7)) << 3);
            }
        }

        unsigned aoff[3], boff[3];
        #pragma unroll
        for (int i = 0; i < 3; ++i) {
            int row = wr * 48 + i * 16 + l15;                    // 0..95
            aoff[i] = (unsigned)row * 128 + ((unsigned)(lq ^ (row & 7)) << 4);
        }
        #pragma unroll
        for (int j = 0; j < 3; ++j) {
            int n = wc * 48 + j * 16 + l15;                      // 0..191
            boff[j] = 12288u + (unsigned)n * 128 + ((unsigned)(lq ^ (n & 7)) << 4);
        }

        f32x4 acc[3][3];
        #pragma unroll
        for (int i = 0; i < 3; ++i)
            #pragma unroll
            for (int j = 0; j < 3; ++j)
                acc[i][j] = (f32x4){0.f, 0.f, 0.f, 0.f};

        #define STG2(buf, kt)                                                  \
            {                                                                  \
                char* base = smem + (buf) * BUF_B;                             \
                int k0 = (kt) * 64;                                            \
                gload16(sp[0] + k0, base + lo[0]);                             \
                gload16(sp[1] + k0, base + lo[1]);                             \
                gload16(sp[2] + k0, base + lo[2]);                             \
                gload16(sp[3] + k0, base + lo[3]);                             \
                if (w < 4) gload16(sp[4] + k0, base + lo[4]);                  \
            }

        #define CMP2(buf)                                                      \
            {                                                                  \
                const char* Bb = smem + (buf) * BUF_B;                         \
                _Pragma("unroll")                                              \
                for (int kx = 0; kx < 128; kx += 64) {                         \
                    bf16x8 af[3], bfr[3];                                      \
                    _Pragma("unroll")                                          \
                    for (int i = 0; i < 3; ++i)                                \
                        af[i] = *(const bf16x8*)(Bb + (aoff[i] ^ kx));         \
                    _Pragma("unroll")                                          \
                    for (int j = 0; j < 3; ++j)                                \
                        bfr[j] = *(const bf16x8*)(Bb + (boff[j] ^ kx));        \
                    _Pragma("unroll")                                          \
                    for (int i = 0; i < 3; ++i)                                \
                        _Pragma("unroll")                                      \
                        for (int j = 0; j < 3; ++j)                            \
                            acc[i][j] = __builtin_amdgcn_mfma_f32_16x16x32_bf16( \
                                af[i], bfr[j], acc[i][j], 0, 0, 0);            \
                }                                                              \
            }

        STG2(0, 0);
        __syncthreads();
        for (int kt = 0; kt < 8; ++kt) {
            int cur = kt & 1;
            if (kt < 7) STG2(cur ^ 1, kt + 1);
            CMP2(cur);
            __syncthreads();
        }

        // ---- epilogue (buffers reusable after final sync)
        float* rowbuf = (float*)smem;            // [4][96]
        float* colbuf = (float*)(smem + 1536);   // [2][192]

        #pragma unroll
        for (int i = 0; i < 3; ++i) {            // rowmax over n (full 192)
            float rm[4];
            #pragma unroll
            for (int r = 0; r < 4; ++r) rm[r] = -1e30f;
            #pragma unroll
            for (int j = 0; j < 3; ++j)
                #pragma unroll
                for (int r = 0; r < 4; ++r)
                    rm[r] = fmaxf(rm[r], acc[i][j][r]);
            #pragma unroll
            for (int msk = 1; msk <= 8; msk <<= 1)
                #pragma unroll
                for (int r = 0; r < 4; ++r)
                    rm[r] = fmaxf(rm[r], __shfl_xor(rm[r], msk));
            if (l15 == 0) {
                #pragma unroll
                for (int r = 0; r < 4; ++r)
                    rowbuf[wc * 96 + wr * 48 + i * 16 + lq * 4 + r] = rm[r];
            }
        }
        #pragma unroll
        for (int j = 0; j < 3; ++j) {            // colmax over m (96 rows, partial)
            float cm = -1e30f;
            #pragma unroll
            for (int i = 0; i < 3; ++i)
                #pragma unroll
                for (int r = 0; r < 4; ++r)
                    cm = fmaxf(cm, acc[i][j][r]);
            cm = fmaxf(cm, __shfl_xor(cm, 16));
            cm = fmaxf(cm, __shfl_xor(cm, 32));
            if (lane < 16) colbuf[wr * HW + wc * 48 + j * 16 + l15] = cm;
        }
        __syncthreads();
        if (tid < 96) {
            float v = fmaxf(fmaxf(rowbuf[tid], rowbuf[96 + tid]),
                            fmaxf(rowbuf[192 + tid], rowbuf[288 + tid]));
            out[((size_t)p * B_ + g) * HW + 96 * h + tid] = v;
        }
        if (tid >= 128 && tid < 320) {
            int n = tid - 128;
            ws2[(size_t)pairid * 384 + h * 192 + n] = fmaxf(colbuf[n], colbuf[HW + n]);
        }
    } else {
        // ================= q/k projection (b, mgrp) =================
        int pb = blockIdx.x - NG2;              // 0..127
        int b = pb >> 2, m0 = (pb & 3) * 48;
        int w4 = w & 3;
        int qc = w4 * 16 + l15;
        bool isq = (w < 4);
        const unsigned short* wp = (isq ? wqb : wkb) + (size_t)qc * CC;
        float bias = isq ? bq[qc] : bk[qc];
        unsigned short* dst = isq ? qo : ko;
        const unsigned short* xb = xt + ((size_t)b * HW + m0) * CC;

        f32x4 a3[3];
        #pragma unroll
        for (int i = 0; i < 3; ++i) a3[i] = (f32x4){0.f, 0.f, 0.f, 0.f};
        for (int kt = 0; kt < 16; ++kt) {
            int ko8 = kt * 32 + lq * 8;
            bf16x8 wf = *(const bf16x8*)(wp + ko8);
            #pragma unroll
            for (int i = 0; i < 3; ++i) {
                bf16x8 af = *(const bf16x8*)(xb + (i * 16 + l15) * CC + ko8);
                a3[i] = __builtin_amdgcn_mfma_f32_16x16x32_bf16(af, wf, a3[i], 0, 0, 0);
            }
        }
        #pragma unroll
        for (int i = 0; i < 3; ++i) {
            #pragma unroll
            for (int r = 0; r < 4; ++r) {
                int m = m0 + i * 16 + lq * 4 + r;
                dst[((size_t)b * HW + m) * C8_ + qc] = f2bf(a3[i][r] + bias);
            }
        }
    }
}

// ---------------- Kernel 3 (fused): pam_energy (0..127) + finalize (128..655)
__global__ __launch_bounds__(256) void energy_fin(
        const unsigned short* __restrict__ qo,
        const unsigned short* __restrict__ ko,
        const float* __restrict__ ws2,
        float* __restrict__ out) {
    int tid = threadIdx.x;
    if (blockIdx.x >= 128) {
        int pairid = blockIdx.x - 128;
        int idx = pairid, g = 0;
        while (idx >= B_ - g) { idx -= B_ - g; ++g; }
        int p = g + idx;
        if (tid < HW)
            out[((size_t)g * B_ + p) * HW + tid] =
                fmaxf(ws2[(size_t)pairid * 384 + tid], ws2[(size_t)pairid * 384 + 192 + tid]);
        return;
    }
    int b = blockIdx.x >> 2, m0 = (blockIdx.x & 3) * 48;
    int w = tid >> 6, lane = tid & 63;
    int l15 = lane & 15, lq = lane >> 4;
    int n0 = w * 48;

    f32x4 acc[3][3];
    #pragma unroll
    for (int i = 0; i < 3; ++i)
        #pragma unroll
        for (int j = 0; j < 3; ++j)
            acc[i][j] = (f32x4){0.f, 0.f, 0.f, 0.f};

    const unsigned short* qb = qo + ((size_t)b * HW + m0) * C8_;
    const unsigned short* kb = ko + ((size_t)b * HW + n0) * C8_;

    #pragma unroll
    for (int kt = 0; kt < 2; ++kt) {
        int ko8 = kt * 32 + lq * 8;
        bf16x8 af[3], bfr[3];
        #pragma unroll
        for (int i = 0; i < 3; ++i)
            af[i] = *(const bf16x8*)(qb + (i * 16 + l15) * C8_ + ko8);
        #pragma unroll
        for (int j = 0; j < 3; ++j)
            bfr[j] = *(const bf16x8*)(kb + (j * 16 + l15) * C8_ + ko8);
        #pragma unroll
        for (int i = 0; i < 3; ++i)
            #pragma unroll
            for (int j = 0; j < 3; ++j)
                acc[i][j] = __builtin_amdgcn_mfma_f32_16x16x32_bf16(af[i], bfr[j], acc[i][j], 0, 0, 0);
    }

    __shared__ float red[4][48];
    #pragma unroll
    for (int i = 0; i < 3; ++i) {
        float rm[4];
        #pragma unroll
        for (int r = 0; r < 4; ++r) rm[r] = -1e30f;
        #pragma unroll
        for (int j = 0; j < 3; ++j)
            #pragma unroll
            for (int r = 0; r < 4; ++r)
                rm[r] = fmaxf(rm[r], acc[i][j][r]);
        #pragma unroll
        for (int msk = 1; msk <= 8; msk <<= 1)
            #pragma unroll
            for (int r = 0; r < 4; ++r)
                rm[r] = fmaxf(rm[r], __shfl_xor(rm[r], msk));
        if (l15 == 0) {
            #pragma unroll
            for (int r = 0; r < 4; ++r)
                red[w][i * 16 + lq * 4 + r] = rm[r];
        }
    }
    __syncthreads();
    if (tid < 48) {
        float v = fmaxf(fmaxf(red[0][tid], red[1][tid]),
                        fmaxf(red[2][tid], red[3][tid]));
        out[((size_t)B_ * B_ + b) * HW + m0 + tid] = v;
    }
}

extern "C" void kernel_launch(void* const* d_in, const int* in_sizes, int n_in,
                              void* d_out, int out_size, void* d_ws, size_t ws_size,
                              hipStream_t stream) {
    (void)in_sizes; (void)n_in; (void)out_size; (void)ws_size;
    const float* x  = (const float*)d_in[0];
    const float* Wq = (const float*)d_in[1];
    const float* bq = (const float*)d_in[2];
    const float* Wk = (const float*)d_in[3];
    const float* bk = (const float*)d_in[4];
    float* out = (float*)d_out;

    char* ws = (char*)d_ws;
    unsigned short* xt  = (unsigned short*)ws;                        // 6291456 B
    unsigned short* wqb = (unsigned short*)(ws + 6291456);            // 65536 B
    unsigned short* wkb = (unsigned short*)(ws + 6291456 + 65536);    // 65536 B
    unsigned short* qbuf = (unsigned short*)(ws + 6291456 + 131072);  // 786432 B
    unsigned short* kbuf = (unsigned short*)(ws + 6291456 + 131072 + 786432);
    float* ws2 = (float*)(ws + 6291456 + 131072 + 2 * 786432);        // 811008 B

    hipFuncSetAttribute((const void*)gram_qk,
                        hipFuncAttributeMaxDynamicSharedMemorySize, SMEM_BYTES);

    prep<<<dim3(104, 8), dim3(256), 0, stream>>>(x, Wq, Wk, xt, wqb, wkb);
    gram_qk<<<dim3(NG2 + 128), dim3(512), SMEM_BYTES, stream>>>(
        xt, wqb, wkb, bq, bk, qbuf, kbuf, out, ws2);
    energy_fin<<<dim3(656), dim3(256), 0, stream>>>(qbuf, kbuf, ws2, out);
}